// Round 1
// baseline (3797.049 us; speedup 1.0000x reference)
//
#include <hip/hip_runtime.h>

#define TT 20
#define HH 20

__device__ __forceinline__ float fast_sigmoid(float x) {
    // 1/(1+exp(-x)) = rcp(1 + exp2(-x*log2(e)))
    float e = __builtin_amdgcn_exp2f(-1.44269504f * x);
    return __builtin_amdgcn_rcpf(1.0f + e);
}

__device__ __forceinline__ float fast_tanh(float x) {
    // tanh(x) = 1 - 2/(exp(2x)+1); saturates to +/-1 without NaN at |x| large
    float e = __builtin_amdgcn_exp2f(2.88539008f * x);
    return 1.0f - 2.0f * __builtin_amdgcn_rcpf(e + 1.0f);
}

__global__ __launch_bounds__(256)
void coord_lstm_kernel(const float* __restrict__ grads,
                       const float* __restrict__ w_ih,
                       const float* __restrict__ w_hh,
                       const float* __restrict__ b_ih,
                       const float* __restrict__ b_hh,
                       const float* __restrict__ w_fc,
                       const float* __restrict__ b_fc,
                       float* __restrict__ out,
                       int N)
{
    __shared__ float s_whh[4 * HH * HH];   // 1600 floats, row-major [gate_row][j]
    __shared__ float s_wih[4 * HH];
    __shared__ float s_bias[4 * HH];
    __shared__ float s_wfc[HH];
    __shared__ float s_bfc;

    for (int i = threadIdx.x; i < 4 * HH * HH; i += 256) s_whh[i] = w_hh[i];
    if (threadIdx.x < 4 * HH) {
        s_wih[threadIdx.x]  = w_ih[threadIdx.x];
        s_bias[threadIdx.x] = b_ih[threadIdx.x] + b_hh[threadIdx.x];
    } else if (threadIdx.x >= 128 && threadIdx.x < 128 + HH) {
        s_wfc[threadIdx.x - 128] = w_fc[threadIdx.x - 128];
    } else if (threadIdx.x == 255) {
        s_bfc = b_fc[0];
    }
    __syncthreads();

    const int n = blockIdx.x * 256 + threadIdx.x;
    if (n >= N) return;

    float h[HH], c[HH];
    #pragma unroll
    for (int u = 0; u < HH; ++u) { h[u] = 0.0f; c[u] = 0.0f; }

    for (int t = 0; t < TT; ++t) {
        const float x = grads[(size_t)t * N + n];
        float hn[HH];
        #pragma unroll
        for (int u = 0; u < HH; ++u) {
            float ai = s_bias[u         ] + x * s_wih[u         ];
            float af = s_bias[u +     HH] + x * s_wih[u +     HH];
            float ag = s_bias[u + 2 * HH] + x * s_wih[u + 2 * HH];
            float ao = s_bias[u + 3 * HH] + x * s_wih[u + 3 * HH];
            #pragma unroll
            for (int j = 0; j < HH; ++j) {
                const float hj = h[j];
                ai += hj * s_whh[(u         ) * HH + j];
                af += hj * s_whh[(u +     HH) * HH + j];
                ag += hj * s_whh[(u + 2 * HH) * HH + j];
                ao += hj * s_whh[(u + 3 * HH) * HH + j];
            }
            const float cn = fast_sigmoid(af) * c[u] + fast_sigmoid(ai) * fast_tanh(ag);
            c[u] = cn;
            hn[u] = fast_sigmoid(ao) * fast_tanh(cn);
        }
        float o = s_bfc;
        #pragma unroll
        for (int u = 0; u < HH; ++u) {
            o += hn[u] * s_wfc[u];
            h[u] = hn[u];
        }
        out[(size_t)t * N + n] = o;
    }
}

extern "C" void kernel_launch(void* const* d_in, const int* in_sizes, int n_in,
                              void* d_out, int out_size, void* d_ws, size_t ws_size,
                              hipStream_t stream) {
    const float* grads = (const float*)d_in[0];
    const float* w_ih  = (const float*)d_in[1];
    const float* w_hh  = (const float*)d_in[2];
    const float* b_ih  = (const float*)d_in[3];
    const float* b_hh  = (const float*)d_in[4];
    const float* w_fc  = (const float*)d_in[5];
    const float* b_fc  = (const float*)d_in[6];
    float* out = (float*)d_out;

    const int N = in_sizes[0] / TT;   // grads is (T, N)
    const int grid = (N + 255) / 256;
    coord_lstm_kernel<<<grid, 256, 0, stream>>>(grads, w_ih, w_hh, b_ih, b_hh,
                                                w_fc, b_fc, out, N);
}